// Round 2
// baseline (351.609 us; speedup 1.0000x reference)
//
#include <hip/hip_runtime.h>

// Cross_IAN: the reference's softmax rows are averaged over the SAME axis the
// softmax normalizes, so mean(softmax(s), axis=2) == 1/S identically.
//   eij[b,s] = 0.5/S + 0.5/S = 1/S
//   out[b,d] = (1/S) * sum_s x0[b,s,d]      (x1, W1, W2 are dead)
// => a single memory-bound mean-reduction over S of x0 [B,S,D] f32.

#define BB 64
#define SS 1024
#define DD 768

#define ND4   (DD / 4)   // 192 float4 per row
#define NSC   16         // s-chunks per (b,d4)  -> 768 blocks, ~3/CU
#define SCHNK (SS / NSC) // 64 s per chunk

__global__ __launch_bounds__(256) void zero_out_kernel(float* __restrict__ out) {
    int i = blockIdx.x * blockDim.x + threadIdx.x;
    if (i < BB * DD) out[i] = 0.0f;
}

__global__ __launch_bounds__(256) void mean_s_kernel(const float* __restrict__ x0,
                                                     float* __restrict__ out) {
    // linear tid -> (b, sc, d4); consecutive threads span d4 => coalesced float4
    int tid  = blockIdx.x * blockDim.x + threadIdx.x;     // 0 .. BB*NSC*ND4-1
    int d4   = tid % ND4;
    int rest = tid / ND4;
    int sc   = rest % NSC;
    int b    = rest / NSC;

    const float4* p = reinterpret_cast<const float4*>(
        x0 + (size_t)b * SS * DD + (size_t)sc * SCHNK * DD) + d4;

    float4 acc = make_float4(0.f, 0.f, 0.f, 0.f);
#pragma unroll 8
    for (int i = 0; i < SCHNK; ++i) {
        float4 v = p[(size_t)i * ND4];
        acc.x += v.x; acc.y += v.y; acc.z += v.z; acc.w += v.w;
    }

    const float inv = 1.0f / (float)SS;
    float* o = out + b * DD + d4 * 4;
    atomicAdd(o + 0, acc.x * inv);
    atomicAdd(o + 1, acc.y * inv);
    atomicAdd(o + 2, acc.z * inv);
    atomicAdd(o + 3, acc.w * inv);
}

extern "C" void kernel_launch(void* const* d_in, const int* in_sizes, int n_in,
                              void* d_out, int out_size, void* d_ws, size_t ws_size,
                              hipStream_t stream) {
    const float* x0 = (const float*)d_in[0];
    float* out = (float*)d_out;

    // d_out is poisoned with 0xAA before every launch — must zero it first.
    zero_out_kernel<<<(BB * DD + 255) / 256, 256, 0, stream>>>(out);

    int total = BB * NSC * ND4;                 // 196608 threads, 768 blocks
    mean_s_kernel<<<total / 256, 256, 0, stream>>>(x0, out);
}